// Round 7
// baseline (4874.000 us; speedup 1.0000x reference)
//
#include <hip/hip_runtime.h>
#include <hip/hip_bf16.h>

// Problem constants (fixed by reference)
#define SEQ    2048
#define BATCH  2
#define MROWS  (SEQ*BATCH)    // 4096
#define EMBED  1024
#define KCTX   3
#define XDIM   (KCTX*EMBED)   // 3072
#define VOCAB  50257
#define VPAD   50304          // Wout^T rows allocated (multiple of 128)
#define GK     1024           // K of the logits GEMM
#define NT2    32             // K-tiles of BK=32
#define NBLKN  197            // ceil(VOCAB/256)
#define NWG    (16*NBLKN)     // 3152 blocks, divisible by 8

using u16 = unsigned short;
typedef __attribute__((ext_vector_type(8))) short   frag_ab;  // 8 bf16
typedef __attribute__((ext_vector_type(4))) float   frag_cd;  // 4 f32

__device__ __forceinline__ u16 f2bf(float f) {
  union { float f; unsigned u; } v; v.f = f;
  unsigned r = v.u + 0x7fffu + ((v.u >> 16) & 1u);
  return (u16)(r >> 16);
}

__device__ __forceinline__ void gload16(const u16* g, u16* l) {
  __builtin_amdgcn_global_load_lds((const __attribute__((address_space(1))) void*)g,
                                   (__attribute__((address_space(3))) void*)l, 16, 0, 0);
}

// ---------------------------------------------------------------------------
// Gather: XB[r][i*1024+c] = bf16(E[tok(r,i)][c]); r = s*BATCH+b
// ---------------------------------------------------------------------------
__global__ void gather_x(const int* __restrict__ tokens,
                         const float* __restrict__ E,
                         u16* __restrict__ XB) {
  const int r = blockIdx.x;
  const int s = r >> 1, b = r & 1;
  #pragma unroll
  for (int i = 0; i < KCTX; ++i) {
    int t = s + i - (KCTX - 1);
    int tok = (t >= 0) ? tokens[t * BATCH + b] : 0;
    const float* src = &E[(size_t)tok * EMBED];
    u16* dst = &XB[(size_t)r * XDIM + i * EMBED];
    int c = threadIdx.x * 4;
    float4 v = *(const float4*)&src[c];
    u16 o[4] = { f2bf(v.x), f2bf(v.y), f2bf(v.z), f2bf(v.w) };
    *(ulong1*)&dst[c] = *(ulong1*)o;
  }
}

// ---------------------------------------------------------------------------
// Transpose + f32->bf16: W (K x N) -> WT (Npad x K). n >= N writes 0.
// ---------------------------------------------------------------------------
__global__ void transpose_cvt(const float* __restrict__ W,
                              u16* __restrict__ WT,
                              int K, int N) {
  __shared__ float tile[32][33];
  const int nb = blockIdx.x * 32, kb = blockIdx.y * 32;
  const int tx = threadIdx.x & 31, ty = threadIdx.x >> 5;
  #pragma unroll
  for (int i = 0; i < 32; i += 8) {
    int k = kb + ty + i, n = nb + tx;
    tile[ty + i][tx] = (n < N) ? W[(size_t)k * N + n] : 0.f;
  }
  __syncthreads();
  #pragma unroll
  for (int i = 0; i < 32; i += 8) {
    int n = nb + ty + i, k = kb + tx;
    WT[(size_t)n * K + k] = f2bf(tile[tx][ty + i]);
  }
}

// ---------------------------------------------------------------------------
// 128x128-tile GEMM (2-phase) for the two small GEMMs. Verified round 1.
// ---------------------------------------------------------------------------
template<int EPI>
__global__ __launch_bounds__(256, 2)
void gemm_bt(const u16* __restrict__ A, const u16* __restrict__ BT,
             const float* __restrict__ bias, void* __restrict__ Cout,
             int K, int Nout) {
  __shared__ u16 lA[128 * 64];
  __shared__ u16 lB[128 * 64];
  const int tid  = threadIdx.x;
  const int wave = tid >> 6, lane = tid & 63;
  const int m0 = blockIdx.y * 128;
  const int n0 = blockIdx.x * 128;
  const int wm = (wave >> 1) * 64;
  const int wn = (wave & 1) * 64;

  frag_cd acc[4][4];
  #pragma unroll
  for (int i = 0; i < 4; ++i)
    #pragma unroll
    for (int j = 0; j < 4; ++j)
      acc[i][j] = (frag_cd)0.f;

  const int srow = lane >> 3;
  const int skc  = (lane & 7) * 8;

  for (int k0 = 0; k0 < K; k0 += 64) {
    #pragma unroll
    for (int i = 0; i < 4; ++i) {
      int chunk = wave * 4 + i;
      int r = chunk * 8 + srow;
      const u16* ga = &A [(size_t)(m0 + r) * K + k0 + skc];
      const u16* gb = &BT[(size_t)(n0 + r) * K + k0 + skc];
      gload16(ga, &lA[chunk * 512 + lane * 8]);
      gload16(gb, &lB[chunk * 512 + lane * 8]);
    }
    __syncthreads();

    #pragma unroll
    for (int kk = 0; kk < 2; ++kk) {
      const int ko = kk * 32 + (lane >> 4) * 8;
      frag_ab af[4], bfr[4];
      #pragma unroll
      for (int i = 0; i < 4; ++i) {
        af[i]  = *(const frag_ab*)&lA[(wm + i * 16 + (lane & 15)) * 64 + ko];
        bfr[i] = *(const frag_ab*)&lB[(wn + i * 16 + (lane & 15)) * 64 + ko];
      }
      #pragma unroll
      for (int i = 0; i < 4; ++i)
        #pragma unroll
        for (int j = 0; j < 4; ++j)
          acc[i][j] = __builtin_amdgcn_mfma_f32_16x16x32_bf16(
              af[i], bfr[j], acc[i][j], 0, 0, 0);
    }
    __syncthreads();
  }

  const int cr = (lane >> 4) * 4;
  const int cc = lane & 15;
  if (EPI == 0) {
    u16* H = (u16*)Cout;
    #pragma unroll
    for (int j = 0; j < 4; ++j) {
      int colg = n0 + wn + j * 16 + cc;
      float bv = bias[colg];
      #pragma unroll
      for (int i = 0; i < 4; ++i)
        #pragma unroll
        for (int t = 0; t < 4; ++t) {
          int rowg = m0 + wm + i * 16 + cr + t;
          float v = acc[i][j][t] + bv;
          v = v / (1.f + __expf(-v));
          H[(size_t)rowg * Nout + colg] = f2bf(v);
        }
    }
  } else {
    float* O = (float*)Cout;
    #pragma unroll
    for (int j = 0; j < 4; ++j) {
      int colg = n0 + wn + j * 16 + cc;
      if (colg < Nout) {
        float bv = bias[colg];
        #pragma unroll
        for (int i = 0; i < 4; ++i)
          #pragma unroll
          for (int t = 0; t < 4; ++t) {
            int rowg = m0 + wm + i * 16 + cr + t;
            O[(size_t)rowg * Nout + colg] = acc[i][j][t] + bv;
          }
      }
    }
  }
}

// ---------------------------------------------------------------------------
// Logits GEMM, round 7: r6's verified loop (256x256 tile, BK=32, 64 KiB LDS,
// 2 blocks/CU TLP, one barrier per K-tile) with the epilogue orientation
// REVERTED to the r1-proven coalescing layout.
//
// MFMA: acc[mf][nf] = mfma(bH[mf], aW[nf], acc) -> D(row=m, col=vocab);
// lane&15 = 16 consecutive vocab cols per 16-lane group = one 64-B segment
// per group (r6's swap put 16 rows per group -> 16B/line RMW -> 22 GB HBM).
// ds_read addressing identical for both operands (row=c, kslot=q), so the
// operand swap requires no address changes.
// ---------------------------------------------------------------------------
#define BARR   asm volatile("s_barrier" ::: "memory")
#define VMCNT0 asm volatile("s_waitcnt vmcnt(0)" ::: "memory")
#define LGKM0  asm volatile("s_waitcnt lgkmcnt(0)" ::: "memory")
#define SCHED0 __builtin_amdgcn_sched_barrier(0)
#define PRIO1  __builtin_amdgcn_s_setprio(1)
#define PRIO0  __builtin_amdgcn_s_setprio(0)

#define DSREAD(DST, AREG, IMM) \
  asm volatile("ds_read_b128 %0, %1 offset:%2" : "=v"(DST) : "v"(AREG), "i"(IMM))

#define STAGE4(WP) { \
  gload16(pa0, (u16*)(smraw + (WP)         + stoff)); \
  gload16(pa1, (u16*)(smraw + (WP) +  8192 + stoff)); \
  gload16(pb0, (u16*)(smraw + (WP) + 32768 + stoff)); \
  gload16(pb1, (u16*)(smraw + (WP) + 40960 + stoff)); }

#define ADV { pa0 += 32; pa1 += 32; pb0 += 32; pb1 += 32; }

#define KTILE(PAR) { \
  STAGE4((PAR ^ 1) * 16384); \
  DSREAD(aW[0], bWreg, (PAR)*16384 + 32768 + 0*1024); \
  DSREAD(aW[1], bWreg, (PAR)*16384 + 32768 + 1*1024); \
  DSREAD(aW[2], bWreg, (PAR)*16384 + 32768 + 2*1024); \
  DSREAD(aW[3], bWreg, (PAR)*16384 + 32768 + 3*1024); \
  DSREAD(bH[0], bHreg, (PAR)*16384 + 0*1024); \
  DSREAD(bH[1], bHreg, (PAR)*16384 + 1*1024); \
  DSREAD(bH[2], bHreg, (PAR)*16384 + 2*1024); \
  DSREAD(bH[3], bHreg, (PAR)*16384 + 3*1024); \
  DSREAD(bH[4], bHreg, (PAR)*16384 + 4*1024); \
  DSREAD(bH[5], bHreg, (PAR)*16384 + 5*1024); \
  DSREAD(bH[6], bHreg, (PAR)*16384 + 6*1024); \
  DSREAD(bH[7], bHreg, (PAR)*16384 + 7*1024); \
  LGKM0; SCHED0; \
  PRIO1; \
  _Pragma("unroll") for (int nf = 0; nf < 4; ++nf) \
  _Pragma("unroll") for (int mf = 0; mf < 8; ++mf) \
    acc[mf][nf] = __builtin_amdgcn_mfma_f32_16x16x32_bf16(bH[mf], aW[nf], acc[mf][nf], 0, 0, 0); \
  PRIO0; SCHED0; \
  VMCNT0; BARR; \
  ADV; }

__global__ __launch_bounds__(512, 4)
void gemm256(const u16* __restrict__ A, const u16* __restrict__ BT,
             const float* __restrict__ bias, float* __restrict__ O) {
  extern __shared__ char smraw[];

  // Bijective chunked XCD swizzle; M-innermost so one XCD reuses one B-panel.
  const int bid = blockIdx.x;
  const int wg  = (bid & 7) * (NWG / 8) + (bid >> 3);
  const int m0  = (wg & 15) * 256;
  const int n0  = (wg >> 4) * 256;

  const int tid  = threadIdx.x;
  const int lane = tid & 63, wave = tid >> 6;
  const int wm = wave >> 2, wn = wave & 3;   // 2 x 4 waves

  // ---- staging constants (gload_lds dest = base + lane*16: linear) ----
  const int stoff = wave * 1024 + lane * 16;               // LDS byte offset
  const int srow  = wave * 16 + (lane >> 2);               // tile row (+g*128)
  const int ke    = ((lane & 3) ^ ((lane >> 3) & 3)) * 8;  // pre-swz k elems

  const u16* pa0 = A + (size_t)(m0 + srow      ) * GK + ke;
  const u16* pa1 = A + (size_t)(m0 + srow + 128) * GK + ke;
  int rb0 = n0 + srow;       if (rb0 > VPAD - 1) rb0 = VPAD - 1;
  int rb1 = n0 + srow + 128; if (rb1 > VPAD - 1) rb1 = VPAD - 1;
  const u16* pb0 = BT + (size_t)rb0 * GK + ke;
  const u16* pb1 = BT + (size_t)rb1 * GK + ke;

  // ---- ds_read address regs (slot ^= (row>>1)&3; row = base + (lane&15)) --
  const unsigned dynbase = (unsigned)(size_t)(__attribute__((address_space(3))) char*)smraw;
  const int c = lane & 15, q = lane >> 4;
  const unsigned swq  = ((unsigned)q << 4) ^ (((unsigned)(c >> 1) & 3u) << 4);
  const unsigned bWreg = dynbase + (unsigned)((wn * 64  + c) * 64) + swq;  // WOT rows (vocab)
  const unsigned bHreg = dynbase + (unsigned)((wm * 128 + c) * 64) + swq;  // H2 rows (m)

  frag_ab aW[4], bH[8];
  frag_cd acc[8][4];
  #pragma unroll
  for (int i = 0; i < 8; ++i)
    #pragma unroll
    for (int j = 0; j < 4; ++j)
      acc[i][j] = (frag_cd)0.f;

  // ---- prologue: stage tile 0 into parity 0 ----
  STAGE4(0);
  ADV;
  VMCNT0; BARR;

  // ---- main loop: 32 K-tiles, parity double-buffered ----
  #pragma unroll 1
  for (int tt = 0; tt < NT2 / 2; ++tt) {
    KTILE(0);
    KTILE(1);
  }

  asm volatile("s_waitcnt vmcnt(0) lgkmcnt(0)" ::: "memory");

  // ---- epilogue: r1-proven layout. col = vocab (lane&15 -> 16 consecutive
  // cols per 16-lane group = 64-B coalesced segments); row = m.
  const int cr = q * 4;                       // m sub-row
  #pragma unroll
  for (int nf = 0; nf < 4; ++nf) {
    const int colg = n0 + wn * 64 + nf * 16 + c;
    if (colg < VOCAB) {
      const float bv = bias[colg];
      #pragma unroll
      for (int mf = 0; mf < 8; ++mf)
        #pragma unroll
        for (int t = 0; t < 4; ++t) {
          const int rowg = m0 + wm * 128 + mf * 16 + cr + t;
          O[(size_t)rowg * VOCAB + colg] = acc[mf][nf][t] + bv;
        }
    }
  }
}

// ---------------------------------------------------------------------------
extern "C" void kernel_launch(void* const* d_in, const int* in_sizes, int n_in,
                              void* d_out, int out_size, void* d_ws, size_t ws_size,
                              hipStream_t stream) {
  const int*   tokens = (const int*)  d_in[0];
  const float* E      = (const float*)d_in[1];
  const float* W1     = (const float*)d_in[2];
  const float* b1     = (const float*)d_in[3];
  const float* W2     = (const float*)d_in[4];
  const float* b2     = (const float*)d_in[5];
  const float* Wout   = (const float*)d_in[6];
  const float* bout   = (const float*)d_in[7];
  float* out = (float*)d_out;

  // Workspace layout (~153.4 MB). Order chosen so gemm256's harmless
  // last-tile over-advance reads (<=1 KB past H2 / WOT) land inside ws.
  char* p = (char*)d_ws;
  u16* XB  = (u16*)p; p += (size_t)MROWS * XDIM  * 2;   // 25.2 MB
  u16* WOT = (u16*)p; p += (size_t)VPAD  * EMBED * 2;   // 103.0 MB (over-read -> H1)
  u16* H1  = (u16*)p; p += (size_t)MROWS * EMBED * 2;   //  8.4 MB
  u16* H2  = (u16*)p; p += (size_t)MROWS * EMBED * 2;   //  8.4 MB (over-read -> W1T)
  u16* W1T = (u16*)p; p += (size_t)EMBED * XDIM  * 2;   //  6.3 MB
  u16* W2T = (u16*)p; p += (size_t)EMBED * EMBED * 2;   //  2.1 MB

  hipFuncSetAttribute((const void*)gemm256,
                      hipFuncAttributeMaxDynamicSharedMemorySize, 65536);

  gather_x<<<MROWS, 256, 0, stream>>>(tokens, E, XB);
  transpose_cvt<<<dim3(EMBED/32, XDIM/32),  256, 0, stream>>>(W1,   W1T, XDIM,  EMBED);
  transpose_cvt<<<dim3(EMBED/32, EMBED/32), 256, 0, stream>>>(W2,   W2T, EMBED, EMBED);
  transpose_cvt<<<dim3(VPAD/32,  EMBED/32), 256, 0, stream>>>(Wout, WOT, EMBED, VOCAB);

  gemm_bt<0><<<dim3(EMBED/128, MROWS/128), 256, 0, stream>>>(XB, W1T, b1, H1, XDIM,  EMBED);
  gemm_bt<0><<<dim3(EMBED/128, MROWS/128), 256, 0, stream>>>(H1, W2T, b2, H2, EMBED, EMBED);

  gemm256<<<NWG, 512, 65536, stream>>>(H2, WOT, bout, out);
}

// Round 8
// 1049.804 us; speedup vs baseline: 4.6428x; 4.6428x over previous
//
#include <hip/hip_runtime.h>
#include <hip/hip_bf16.h>

// Problem constants (fixed by reference)
#define SEQ    2048
#define BATCH  2
#define MROWS  (SEQ*BATCH)    // 4096
#define EMBED  1024
#define KCTX   3
#define XDIM   (KCTX*EMBED)   // 3072
#define VOCAB  50257
#define VPAD   50304          // Wout^T rows allocated (multiple of 128)
#define GK     1024           // K of the logits GEMM
#define NT2    32             // K-tiles of BK=32
#define NBLKN  197            // ceil(VOCAB/256)
#define NWG    (16*NBLKN)     // 3152 blocks, divisible by 8

using u16 = unsigned short;
typedef __attribute__((ext_vector_type(8))) short   frag_ab;  // 8 bf16
typedef __attribute__((ext_vector_type(4))) float   frag_cd;  // 4 f32

__device__ __forceinline__ u16 f2bf(float f) {
  union { float f; unsigned u; } v; v.f = f;
  unsigned r = v.u + 0x7fffu + ((v.u >> 16) & 1u);
  return (u16)(r >> 16);
}

__device__ __forceinline__ void gload16(const u16* g, u16* l) {
  __builtin_amdgcn_global_load_lds((const __attribute__((address_space(1))) void*)g,
                                   (__attribute__((address_space(3))) void*)l, 16, 0, 0);
}

// ---------------------------------------------------------------------------
// Gather: XB[r][i*1024+c] = bf16(E[tok(r,i)][c]); r = s*BATCH+b
// ---------------------------------------------------------------------------
__global__ void gather_x(const int* __restrict__ tokens,
                         const float* __restrict__ E,
                         u16* __restrict__ XB) {
  const int r = blockIdx.x;
  const int s = r >> 1, b = r & 1;
  #pragma unroll
  for (int i = 0; i < KCTX; ++i) {
    int t = s + i - (KCTX - 1);
    int tok = (t >= 0) ? tokens[t * BATCH + b] : 0;
    const float* src = &E[(size_t)tok * EMBED];
    u16* dst = &XB[(size_t)r * XDIM + i * EMBED];
    int c = threadIdx.x * 4;
    float4 v = *(const float4*)&src[c];
    u16 o[4] = { f2bf(v.x), f2bf(v.y), f2bf(v.z), f2bf(v.w) };
    *(ulong1*)&dst[c] = *(ulong1*)o;
  }
}

// ---------------------------------------------------------------------------
// Transpose + f32->bf16: W (K x N) -> WT (Npad x K). n >= N writes 0.
// ---------------------------------------------------------------------------
__global__ void transpose_cvt(const float* __restrict__ W,
                              u16* __restrict__ WT,
                              int K, int N) {
  __shared__ float tile[32][33];
  const int nb = blockIdx.x * 32, kb = blockIdx.y * 32;
  const int tx = threadIdx.x & 31, ty = threadIdx.x >> 5;
  #pragma unroll
  for (int i = 0; i < 32; i += 8) {
    int k = kb + ty + i, n = nb + tx;
    tile[ty + i][tx] = (n < N) ? W[(size_t)k * N + n] : 0.f;
  }
  __syncthreads();
  #pragma unroll
  for (int i = 0; i < 32; i += 8) {
    int n = nb + ty + i, k = kb + tx;
    WT[(size_t)n * K + k] = f2bf(tile[tx][ty + i]);
  }
}

// ---------------------------------------------------------------------------
// 128x128-tile GEMM (2-phase) for the two small GEMMs. Verified round 1.
// ---------------------------------------------------------------------------
template<int EPI>
__global__ __launch_bounds__(256, 2)
void gemm_bt(const u16* __restrict__ A, const u16* __restrict__ BT,
             const float* __restrict__ bias, void* __restrict__ Cout,
             int K, int Nout) {
  __shared__ u16 lA[128 * 64];
  __shared__ u16 lB[128 * 64];
  const int tid  = threadIdx.x;
  const int wave = tid >> 6, lane = tid & 63;
  const int m0 = blockIdx.y * 128;
  const int n0 = blockIdx.x * 128;
  const int wm = (wave >> 1) * 64;
  const int wn = (wave & 1) * 64;

  frag_cd acc[4][4];
  #pragma unroll
  for (int i = 0; i < 4; ++i)
    #pragma unroll
    for (int j = 0; j < 4; ++j)
      acc[i][j] = (frag_cd)0.f;

  const int srow = lane >> 3;
  const int skc  = (lane & 7) * 8;

  for (int k0 = 0; k0 < K; k0 += 64) {
    #pragma unroll
    for (int i = 0; i < 4; ++i) {
      int chunk = wave * 4 + i;
      int r = chunk * 8 + srow;
      const u16* ga = &A [(size_t)(m0 + r) * K + k0 + skc];
      const u16* gb = &BT[(size_t)(n0 + r) * K + k0 + skc];
      gload16(ga, &lA[chunk * 512 + lane * 8]);
      gload16(gb, &lB[chunk * 512 + lane * 8]);
    }
    __syncthreads();

    #pragma unroll
    for (int kk = 0; kk < 2; ++kk) {
      const int ko = kk * 32 + (lane >> 4) * 8;
      frag_ab af[4], bfr[4];
      #pragma unroll
      for (int i = 0; i < 4; ++i) {
        af[i]  = *(const frag_ab*)&lA[(wm + i * 16 + (lane & 15)) * 64 + ko];
        bfr[i] = *(const frag_ab*)&lB[(wn + i * 16 + (lane & 15)) * 64 + ko];
      }
      #pragma unroll
      for (int i = 0; i < 4; ++i)
        #pragma unroll
        for (int j = 0; j < 4; ++j)
          acc[i][j] = __builtin_amdgcn_mfma_f32_16x16x32_bf16(
              af[i], bfr[j], acc[i][j], 0, 0, 0);
    }
    __syncthreads();
  }

  const int cr = (lane >> 4) * 4;
  const int cc = lane & 15;
  if (EPI == 0) {
    u16* H = (u16*)Cout;
    #pragma unroll
    for (int j = 0; j < 4; ++j) {
      int colg = n0 + wn + j * 16 + cc;
      float bv = bias[colg];
      #pragma unroll
      for (int i = 0; i < 4; ++i)
        #pragma unroll
        for (int t = 0; t < 4; ++t) {
          int rowg = m0 + wm + i * 16 + cr + t;
          float v = acc[i][j][t] + bv;
          v = v / (1.f + __expf(-v));
          H[(size_t)rowg * Nout + colg] = f2bf(v);
        }
    }
  } else {
    float* O = (float*)Cout;
    #pragma unroll
    for (int j = 0; j < 4; ++j) {
      int colg = n0 + wn + j * 16 + cc;
      if (colg < Nout) {
        float bv = bias[colg];
        #pragma unroll
        for (int i = 0; i < 4; ++i)
          #pragma unroll
          for (int t = 0; t < 4; ++t) {
            int rowg = m0 + wm + i * 16 + cr + t;
            O[(size_t)rowg * Nout + colg] = acc[i][j][t] + bv;
          }
      }
    }
  }
}

// ---------------------------------------------------------------------------
// Logits GEMM, round 8: identical to round 7 EXCEPT __launch_bounds__(512, 2).
//
// r6/r7 POST-MORTEM: __launch_bounds__(512, 4) halved the register budget
// (VGPR_Count 108 -> 64) and spilled the K-loop working set to scratch —
// that was the 14 GB WRITE / 8 GB FETCH, not store orientation. (512, 2)
// restores the no-spill allocation; 64 KiB LDS still permits 2 blocks/CU
// (regs ~110 VGPR + 128 AGPR ~= 240/wave, 4 waves/SIMD fits the 2048 pool).
//
// Loop per K-tile: stage 4 gloads (next parity) -> 12 asm ds_reads ->
// lgkm0 -> 32 MFMA (D row=m, col=vocab) -> vmcnt(0) -> barrier.
// Epilogue: lane&15 = 16 consecutive vocab cols = 64-B segments (r1-proven).
// ---------------------------------------------------------------------------
#define BARR   asm volatile("s_barrier" ::: "memory")
#define VMCNT0 asm volatile("s_waitcnt vmcnt(0)" ::: "memory")
#define LGKM0  asm volatile("s_waitcnt lgkmcnt(0)" ::: "memory")
#define SCHED0 __builtin_amdgcn_sched_barrier(0)
#define PRIO1  __builtin_amdgcn_s_setprio(1)
#define PRIO0  __builtin_amdgcn_s_setprio(0)

#define DSREAD(DST, AREG, IMM) \
  asm volatile("ds_read_b128 %0, %1 offset:%2" : "=v"(DST) : "v"(AREG), "i"(IMM))

#define STAGE4(WP) { \
  gload16(pa0, (u16*)(smraw + (WP)         + stoff)); \
  gload16(pa1, (u16*)(smraw + (WP) +  8192 + stoff)); \
  gload16(pb0, (u16*)(smraw + (WP) + 32768 + stoff)); \
  gload16(pb1, (u16*)(smraw + (WP) + 40960 + stoff)); }

#define ADV { pa0 += 32; pa1 += 32; pb0 += 32; pb1 += 32; }

#define KTILE(PAR) { \
  STAGE4((PAR ^ 1) * 16384); \
  DSREAD(aW[0], bWreg, (PAR)*16384 + 32768 + 0*1024); \
  DSREAD(aW[1], bWreg, (PAR)*16384 + 32768 + 1*1024); \
  DSREAD(aW[2], bWreg, (PAR)*16384 + 32768 + 2*1024); \
  DSREAD(aW[3], bWreg, (PAR)*16384 + 32768 + 3*1024); \
  DSREAD(bH[0], bHreg, (PAR)*16384 + 0*1024); \
  DSREAD(bH[1], bHreg, (PAR)*16384 + 1*1024); \
  DSREAD(bH[2], bHreg, (PAR)*16384 + 2*1024); \
  DSREAD(bH[3], bHreg, (PAR)*16384 + 3*1024); \
  DSREAD(bH[4], bHreg, (PAR)*16384 + 4*1024); \
  DSREAD(bH[5], bHreg, (PAR)*16384 + 5*1024); \
  DSREAD(bH[6], bHreg, (PAR)*16384 + 6*1024); \
  DSREAD(bH[7], bHreg, (PAR)*16384 + 7*1024); \
  LGKM0; SCHED0; \
  PRIO1; \
  _Pragma("unroll") for (int nf = 0; nf < 4; ++nf) \
  _Pragma("unroll") for (int mf = 0; mf < 8; ++mf) \
    acc[mf][nf] = __builtin_amdgcn_mfma_f32_16x16x32_bf16(bH[mf], aW[nf], acc[mf][nf], 0, 0, 0); \
  PRIO0; SCHED0; \
  VMCNT0; BARR; \
  ADV; }

__global__ __launch_bounds__(512, 2)
void gemm256(const u16* __restrict__ A, const u16* __restrict__ BT,
             const float* __restrict__ bias, float* __restrict__ O) {
  extern __shared__ char smraw[];

  // Bijective chunked XCD swizzle; M-innermost so one XCD reuses one B-panel.
  const int bid = blockIdx.x;
  const int wg  = (bid & 7) * (NWG / 8) + (bid >> 3);
  const int m0  = (wg & 15) * 256;
  const int n0  = (wg >> 4) * 256;

  const int tid  = threadIdx.x;
  const int lane = tid & 63, wave = tid >> 6;
  const int wm = wave >> 2, wn = wave & 3;   // 2 x 4 waves

  // ---- staging constants (gload_lds dest = base + lane*16: linear) ----
  const int stoff = wave * 1024 + lane * 16;               // LDS byte offset
  const int srow  = wave * 16 + (lane >> 2);               // tile row (+g*128)
  const int ke    = ((lane & 3) ^ ((lane >> 3) & 3)) * 8;  // pre-swz k elems

  const u16* pa0 = A + (size_t)(m0 + srow      ) * GK + ke;
  const u16* pa1 = A + (size_t)(m0 + srow + 128) * GK + ke;
  int rb0 = n0 + srow;       if (rb0 > VPAD - 1) rb0 = VPAD - 1;
  int rb1 = n0 + srow + 128; if (rb1 > VPAD - 1) rb1 = VPAD - 1;
  const u16* pb0 = BT + (size_t)rb0 * GK + ke;
  const u16* pb1 = BT + (size_t)rb1 * GK + ke;

  // ---- ds_read address regs (slot ^= (row>>1)&3; row = base + (lane&15)) --
  const unsigned dynbase = (unsigned)(size_t)(__attribute__((address_space(3))) char*)smraw;
  const int c = lane & 15, q = lane >> 4;
  const unsigned swq  = ((unsigned)q << 4) ^ (((unsigned)(c >> 1) & 3u) << 4);
  const unsigned bWreg = dynbase + (unsigned)((wn * 64  + c) * 64) + swq;  // WOT rows (vocab)
  const unsigned bHreg = dynbase + (unsigned)((wm * 128 + c) * 64) + swq;  // H2 rows (m)

  frag_ab aW[4], bH[8];
  frag_cd acc[8][4];
  #pragma unroll
  for (int i = 0; i < 8; ++i)
    #pragma unroll
    for (int j = 0; j < 4; ++j)
      acc[i][j] = (frag_cd)0.f;

  // ---- prologue: stage tile 0 into parity 0 ----
  STAGE4(0);
  ADV;
  VMCNT0; BARR;

  // ---- main loop: 32 K-tiles, parity double-buffered ----
  #pragma unroll 1
  for (int tt = 0; tt < NT2 / 2; ++tt) {
    KTILE(0);
    KTILE(1);
  }

  asm volatile("s_waitcnt vmcnt(0) lgkmcnt(0)" ::: "memory");

  // ---- epilogue: col = vocab (lane&15 -> 16 consecutive cols per 16-lane
  // group = 64-B coalesced segments); row = m.
  const int cr = q * 4;                       // m sub-row
  #pragma unroll
  for (int nf = 0; nf < 4; ++nf) {
    const int colg = n0 + wn * 64 + nf * 16 + c;
    if (colg < VOCAB) {
      const float bv = bias[colg];
      #pragma unroll
      for (int mf = 0; mf < 8; ++mf)
        #pragma unroll
        for (int t = 0; t < 4; ++t) {
          const int rowg = m0 + wm * 128 + mf * 16 + cr + t;
          O[(size_t)rowg * VOCAB + colg] = acc[mf][nf][t] + bv;
        }
    }
  }
}

// ---------------------------------------------------------------------------
extern "C" void kernel_launch(void* const* d_in, const int* in_sizes, int n_in,
                              void* d_out, int out_size, void* d_ws, size_t ws_size,
                              hipStream_t stream) {
  const int*   tokens = (const int*)  d_in[0];
  const float* E      = (const float*)d_in[1];
  const float* W1     = (const float*)d_in[2];
  const float* b1     = (const float*)d_in[3];
  const float* W2     = (const float*)d_in[4];
  const float* b2     = (const float*)d_in[5];
  const float* Wout   = (const float*)d_in[6];
  const float* bout   = (const float*)d_in[7];
  float* out = (float*)d_out;

  // Workspace layout (~153.4 MB). Order chosen so gemm256's harmless
  // last-tile over-advance reads (<=1 KB past H2 / WOT) land inside ws.
  char* p = (char*)d_ws;
  u16* XB  = (u16*)p; p += (size_t)MROWS * XDIM  * 2;   // 25.2 MB
  u16* WOT = (u16*)p; p += (size_t)VPAD  * EMBED * 2;   // 103.0 MB (over-read -> H1)
  u16* H1  = (u16*)p; p += (size_t)MROWS * EMBED * 2;   //  8.4 MB
  u16* H2  = (u16*)p; p += (size_t)MROWS * EMBED * 2;   //  8.4 MB (over-read -> W1T)
  u16* W1T = (u16*)p; p += (size_t)EMBED * XDIM  * 2;   //  6.3 MB
  u16* W2T = (u16*)p; p += (size_t)EMBED * EMBED * 2;   //  2.1 MB

  hipFuncSetAttribute((const void*)gemm256,
                      hipFuncAttributeMaxDynamicSharedMemorySize, 65536);

  gather_x<<<MROWS, 256, 0, stream>>>(tokens, E, XB);
  transpose_cvt<<<dim3(EMBED/32, XDIM/32),  256, 0, stream>>>(W1,   W1T, XDIM,  EMBED);
  transpose_cvt<<<dim3(EMBED/32, EMBED/32), 256, 0, stream>>>(W2,   W2T, EMBED, EMBED);
  transpose_cvt<<<dim3(VPAD/32,  EMBED/32), 256, 0, stream>>>(Wout, WOT, EMBED, VOCAB);

  gemm_bt<0><<<dim3(EMBED/128, MROWS/128), 256, 0, stream>>>(XB, W1T, b1, H1, XDIM,  EMBED);
  gemm_bt<0><<<dim3(EMBED/128, MROWS/128), 256, 0, stream>>>(H1, W2T, b2, H2, EMBED, EMBED);

  gemm256<<<NWG, 512, 65536, stream>>>(H2, WOT, bout, out);
}

// Round 9
// 812.015 us; speedup vs baseline: 6.0023x; 1.2928x over previous
//
#include <hip/hip_runtime.h>
#include <hip/hip_bf16.h>

// Problem constants (fixed by reference)
#define SEQ    2048
#define BATCH  2
#define MROWS  (SEQ*BATCH)    // 4096
#define EMBED  1024
#define KCTX   3
#define XDIM   (KCTX*EMBED)   // 3072
#define VOCAB  50257
#define VPAD   50304          // Wout^T rows allocated (multiple of 128)
#define GK     1024           // K of the logits GEMM
#define NT2    32             // K-tiles of BK=32
#define NBLKN  197            // ceil(VOCAB/256)
#define NWG    (16*NBLKN)     // 3152 blocks, divisible by 8

using u16 = unsigned short;
typedef __attribute__((ext_vector_type(8))) short   frag_ab;  // 8 bf16
typedef __attribute__((ext_vector_type(4))) float   frag_cd;  // 4 f32

__device__ __forceinline__ u16 f2bf(float f) {
  union { float f; unsigned u; } v; v.f = f;
  unsigned r = v.u + 0x7fffu + ((v.u >> 16) & 1u);
  return (u16)(r >> 16);
}

__device__ __forceinline__ void gload16(const u16* g, const u16* l) {
  __builtin_amdgcn_global_load_lds((const __attribute__((address_space(1))) void*)g,
                                   (__attribute__((address_space(3))) void*)l, 16, 0, 0);
}

// ---------------------------------------------------------------------------
// Gather: XB[r][i*1024+c] = bf16(E[tok(r,i)][c]); r = s*BATCH+b
// ---------------------------------------------------------------------------
__global__ void gather_x(const int* __restrict__ tokens,
                         const float* __restrict__ E,
                         u16* __restrict__ XB) {
  const int r = blockIdx.x;
  const int s = r >> 1, b = r & 1;
  #pragma unroll
  for (int i = 0; i < KCTX; ++i) {
    int t = s + i - (KCTX - 1);
    int tok = (t >= 0) ? tokens[t * BATCH + b] : 0;
    const float* src = &E[(size_t)tok * EMBED];
    u16* dst = &XB[(size_t)r * XDIM + i * EMBED];
    int c = threadIdx.x * 4;
    float4 v = *(const float4*)&src[c];
    u16 o[4] = { f2bf(v.x), f2bf(v.y), f2bf(v.z), f2bf(v.w) };
    *(ulong1*)&dst[c] = *(ulong1*)o;
  }
}

// ---------------------------------------------------------------------------
// Transpose + f32->bf16: W (K x N) -> WT (Npad x K). n >= N writes 0.
// ---------------------------------------------------------------------------
__global__ void transpose_cvt(const float* __restrict__ W,
                              u16* __restrict__ WT,
                              int K, int N) {
  __shared__ float tile[32][33];
  const int nb = blockIdx.x * 32, kb = blockIdx.y * 32;
  const int tx = threadIdx.x & 31, ty = threadIdx.x >> 5;
  #pragma unroll
  for (int i = 0; i < 32; i += 8) {
    int k = kb + ty + i, n = nb + tx;
    tile[ty + i][tx] = (n < N) ? W[(size_t)k * N + n] : 0.f;
  }
  __syncthreads();
  #pragma unroll
  for (int i = 0; i < 32; i += 8) {
    int n = nb + ty + i, k = kb + tx;
    WT[(size_t)n * K + k] = f2bf(tile[tx][ty + i]);
  }
}

// ---------------------------------------------------------------------------
// 128x128-tile GEMM (2-phase) for the two small GEMMs. Verified round 1.
// ---------------------------------------------------------------------------
template<int EPI>
__global__ __launch_bounds__(256, 2)
void gemm_bt(const u16* __restrict__ A, const u16* __restrict__ BT,
             const float* __restrict__ bias, void* __restrict__ Cout,
             int K, int Nout) {
  __shared__ u16 lA[128 * 64];
  __shared__ u16 lB[128 * 64];
  const int tid  = threadIdx.x;
  const int wave = tid >> 6, lane = tid & 63;
  const int m0 = blockIdx.y * 128;
  const int n0 = blockIdx.x * 128;
  const int wm = (wave >> 1) * 64;
  const int wn = (wave & 1) * 64;

  frag_cd acc[4][4];
  #pragma unroll
  for (int i = 0; i < 4; ++i)
    #pragma unroll
    for (int j = 0; j < 4; ++j)
      acc[i][j] = (frag_cd)0.f;

  const int srow = lane >> 3;
  const int skc  = (lane & 7) * 8;

  for (int k0 = 0; k0 < K; k0 += 64) {
    #pragma unroll
    for (int i = 0; i < 4; ++i) {
      int chunk = wave * 4 + i;
      int r = chunk * 8 + srow;
      const u16* ga = &A [(size_t)(m0 + r) * K + k0 + skc];
      const u16* gb = &BT[(size_t)(n0 + r) * K + k0 + skc];
      gload16(ga, &lA[chunk * 512 + lane * 8]);
      gload16(gb, &lB[chunk * 512 + lane * 8]);
    }
    __syncthreads();

    #pragma unroll
    for (int kk = 0; kk < 2; ++kk) {
      const int ko = kk * 32 + (lane >> 4) * 8;
      frag_ab af[4], bfr[4];
      #pragma unroll
      for (int i = 0; i < 4; ++i) {
        af[i]  = *(const frag_ab*)&lA[(wm + i * 16 + (lane & 15)) * 64 + ko];
        bfr[i] = *(const frag_ab*)&lB[(wn + i * 16 + (lane & 15)) * 64 + ko];
      }
      #pragma unroll
      for (int i = 0; i < 4; ++i)
        #pragma unroll
        for (int j = 0; j < 4; ++j)
          acc[i][j] = __builtin_amdgcn_mfma_f32_16x16x32_bf16(
              af[i], bfr[j], acc[i][j], 0, 0, 0);
    }
    __syncthreads();
  }

  const int cr = (lane >> 4) * 4;
  const int cc = lane & 15;
  if (EPI == 0) {
    u16* H = (u16*)Cout;
    #pragma unroll
    for (int j = 0; j < 4; ++j) {
      int colg = n0 + wn + j * 16 + cc;
      float bv = bias[colg];
      #pragma unroll
      for (int i = 0; i < 4; ++i)
        #pragma unroll
        for (int t = 0; t < 4; ++t) {
          int rowg = m0 + wm + i * 16 + cr + t;
          float v = acc[i][j][t] + bv;
          v = v / (1.f + __expf(-v));
          H[(size_t)rowg * Nout + colg] = f2bf(v);
        }
    }
  } else {
    float* O = (float*)Cout;
    #pragma unroll
    for (int j = 0; j < 4; ++j) {
      int colg = n0 + wn + j * 16 + cc;
      if (colg < Nout) {
        float bv = bias[colg];
        #pragma unroll
        for (int i = 0; i < 4; ++i)
          #pragma unroll
          for (int t = 0; t < 4; ++t) {
            int rowg = m0 + wm + i * 16 + cr + t;
            O[(size_t)rowg * Nout + colg] = acc[i][j][t] + bv;
          }
      }
    }
  }
}

// ---------------------------------------------------------------------------
// Logits GEMM, round 9.
// (a) Depth-2 prefetch: 3 LDS parities (96 KiB), counted vmcnt(4), ONE
//     barrier per K-tile, loads never drained to 0 in the main loop.
//     Ledger: at tile-t entry outstanding = stages{t,t+1} = 8 loads;
//     vmcnt(4) retires exactly t's 4; barrier seals cross-wave; then
//     stage(t+2) is WAR-safe (its parity's readers passed the barrier).
// (b) Full-line stores: epilogue round-trips acc through a per-wave
//     stride-68-padded LDS slice (double-buffered by mf parity) so each
//     quarter-wave stores 256 B contiguous f32x4 -> whole 128 B lines per
//     instruction. r1-r8 stores were 64 B sectors whose line-halves arrived
//     32 instrs apart -> L2 evicted between halves -> 1.64x write + RMW
//     fetch (the ~2.5 TB/s effective-HBM floor all rounds shared).
//
// LDS parity p at p*32768: H2 tile [256][64B] at +0, WOT tile at +16384.
// ---------------------------------------------------------------------------
#define BARR   asm volatile("s_barrier" ::: "memory")
#define VMCNT4 asm volatile("s_waitcnt vmcnt(4)" ::: "memory")
#define LGKM0  asm volatile("s_waitcnt lgkmcnt(0)" ::: "memory")
#define SCHED0 __builtin_amdgcn_sched_barrier(0)
#define PRIO1  __builtin_amdgcn_s_setprio(1)
#define PRIO0  __builtin_amdgcn_s_setprio(0)

#define DSREAD(DST, AREG, IMM) \
  asm volatile("ds_read_b128 %0, %1 offset:%2" : "=v"(DST) : "v"(AREG), "i"(IMM))

#define ADV { pa0 += 32; pa1 += 32; pb0 += 32; pb1 += 32; }

// One K-tile: REGH/REGW = ds_read base regs (lo: par0/1, hi: par2),
// HIMM/WIMM = parity byte offset for reads, WP = stage-dest parity bytes.
#define KT(REGH, REGW, HIMM, WIMM, WP) { \
  VMCNT4; BARR; \
  gload16(pa0, (const u16*)(smraw + (WP)         + stoff)); \
  gload16(pa1, (const u16*)(smraw + (WP) +  8192 + stoff)); \
  gload16(pb0, (const u16*)(smraw + (WP) + 16384 + stoff)); \
  gload16(pb1, (const u16*)(smraw + (WP) + 24576 + stoff)); \
  ADV; \
  DSREAD(hF[0], REGH, (HIMM) + 0*1024); \
  DSREAD(hF[1], REGH, (HIMM) + 1*1024); \
  DSREAD(hF[2], REGH, (HIMM) + 2*1024); \
  DSREAD(hF[3], REGH, (HIMM) + 3*1024); \
  DSREAD(hF[4], REGH, (HIMM) + 4*1024); \
  DSREAD(hF[5], REGH, (HIMM) + 5*1024); \
  DSREAD(hF[6], REGH, (HIMM) + 6*1024); \
  DSREAD(hF[7], REGH, (HIMM) + 7*1024); \
  DSREAD(wF[0], REGW, (WIMM) + 0*1024); \
  DSREAD(wF[1], REGW, (WIMM) + 1*1024); \
  DSREAD(wF[2], REGW, (WIMM) + 2*1024); \
  DSREAD(wF[3], REGW, (WIMM) + 3*1024); \
  LGKM0; SCHED0; \
  PRIO1; \
  _Pragma("unroll") for (int nf = 0; nf < 4; ++nf) \
  _Pragma("unroll") for (int mf = 0; mf < 8; ++mf) \
    acc[mf][nf] = __builtin_amdgcn_mfma_f32_16x16x32_bf16(hF[mf], wF[nf], acc[mf][nf], 0, 0, 0); \
  PRIO0; SCHED0; }

__global__ __launch_bounds__(512, 2)
void gemm256(const u16* __restrict__ A, const u16* __restrict__ BT,
             const float* __restrict__ bias, float* __restrict__ O) {
  extern __shared__ char smraw[];

  // Bijective chunked XCD swizzle; M-innermost so one XCD reuses one B-panel.
  const int bid = blockIdx.x;
  const int wg  = (bid & 7) * (NWG / 8) + (bid >> 3);
  const int m0  = (wg & 15) * 256;
  const int n0  = (wg >> 4) * 256;

  const int tid  = threadIdx.x;
  const int lane = tid & 63, wave = tid >> 6;
  const int wm = wave >> 2, wn = wave & 3;   // 2 x 4 waves

  // ---- staging constants (gload_lds dest = base + lane*16: linear) ----
  const int stoff = wave * 1024 + lane * 16;               // LDS byte offset
  const int srow  = wave * 16 + (lane >> 2);               // tile row (+128 for *1)
  const int ke    = ((lane & 3) ^ ((lane >> 3) & 3)) * 8;  // pre-swz k elems

  const u16* pa0 = A + (size_t)(m0 + srow      ) * GK + ke;
  const u16* pa1 = A + (size_t)(m0 + srow + 128) * GK + ke;
  int rb0 = n0 + srow;       if (rb0 > VPAD - 1) rb0 = VPAD - 1;
  int rb1 = n0 + srow + 128; if (rb1 > VPAD - 1) rb1 = VPAD - 1;
  const u16* pb0 = BT + (size_t)rb0 * GK + ke;
  const u16* pb1 = BT + (size_t)rb1 * GK + ke;

  // ---- ds_read base regs (swizzle: 16B-slot ^= (row>>1)&3) ----
  const unsigned dynbase = (unsigned)(size_t)(__attribute__((address_space(3))) char*)smraw;
  const int c = lane & 15, q = lane >> 4;
  const unsigned swq  = ((unsigned)q << 4) ^ (((unsigned)(c >> 1) & 3u) << 4);
  const unsigned regH_lo = dynbase + (unsigned)((wm * 128 + c) * 64) + swq;            // H2 rows (m)
  const unsigned regW_lo = dynbase + 16384u + (unsigned)((wn * 64 + c) * 64) + swq;    // WOT rows (vocab)
  const unsigned regH_hi = regH_lo + 65536u;   // parity 2
  const unsigned regW_hi = regW_lo + 65536u;

  frag_ab hF[8], wF[4];
  frag_cd acc[8][4];
  #pragma unroll
  for (int i = 0; i < 8; ++i)
    #pragma unroll
    for (int j = 0; j < 4; ++j)
      acc[i][j] = (frag_cd)0.f;

  // ---- prologue: stage tiles 0 -> par0, 1 -> par1 ----
  gload16(pa0, (const u16*)(smraw +     0 + stoff));
  gload16(pa1, (const u16*)(smraw +  8192 + stoff));
  gload16(pb0, (const u16*)(smraw + 16384 + stoff));
  gload16(pb1, (const u16*)(smraw + 24576 + stoff));
  ADV;
  gload16(pa0, (const u16*)(smraw + 32768 +     0 + stoff));
  gload16(pa1, (const u16*)(smraw + 32768 +  8192 + stoff));
  gload16(pb0, (const u16*)(smraw + 32768 + 16384 + stoff));
  gload16(pb1, (const u16*)(smraw + 32768 + 24576 + stoff));
  ADV;

  // ---- main loop: 32 K-tiles = 10 x (par0,par1,par2) + par0,par1 ----
  #pragma unroll 1
  for (int tt = 0; tt < 10; ++tt) {
    KT(regH_lo, regW_lo,     0,     0, 65536);   // read par0, stage -> par2
    KT(regH_lo, regW_lo, 32768, 32768,     0);   // read par1, stage -> par0
    KT(regH_hi, regW_hi,     0,     0, 32768);   // read par2, stage -> par1
  }
  KT(regH_lo, regW_lo,     0,     0, 65536);     // t=30
  KT(regH_lo, regW_lo, 32768, 32768,     0);     // t=31 (stages are garbage, in-ws)

  // drain garbage stages + all LDS ops, then barrier before LDS reuse
  asm volatile("s_waitcnt vmcnt(0) lgkmcnt(0)" ::: "memory");
  BARR;

  // ---- epilogue: re-layout through LDS -> full-128B-line stores ----
  // Per-wave slice [16][68] f32 (stride-68 kills write conflicts), double-
  // buffered by mf parity. Quarter-wave (fixed q) stores one row's 64 cols
  // = 256 B contiguous.
  float* lfs = (float*)smraw;
  const int colg = n0 + wn * 64 + c * 4;
  #pragma unroll
  for (int mf = 0; mf < 8; ++mf) {
    const int lbase = wave * 1088 + (mf & 1) * 8704;
    #pragma unroll
    for (int nf = 0; nf < 4; ++nf)
      #pragma unroll
      for (int t = 0; t < 4; ++t)
        lfs[lbase + (q * 4 + t) * 68 + nf * 16 + c] = acc[mf][nf][t];
    #pragma unroll
    for (int p = 0; p < 4; ++p) {
      frag_cd v = *(const frag_cd*)&lfs[lbase + (p * 4 + q) * 68 + c * 4];
      const int rowg = m0 + wm * 128 + mf * 16 + p * 4 + q;
      if (colg + 3 < VOCAB) {
        frag_cd bv = *(const frag_cd*)&bias[colg];
        v += bv;
        *(frag_cd*)&O[(size_t)rowg * VOCAB + colg] = v;
      } else {
        #pragma unroll
        for (int t = 0; t < 4; ++t)
          if (colg + t < VOCAB)
            O[(size_t)rowg * VOCAB + colg + t] = v[t] + bias[colg + t];
      }
    }
  }
}

// ---------------------------------------------------------------------------
extern "C" void kernel_launch(void* const* d_in, const int* in_sizes, int n_in,
                              void* d_out, int out_size, void* d_ws, size_t ws_size,
                              hipStream_t stream) {
  const int*   tokens = (const int*)  d_in[0];
  const float* E      = (const float*)d_in[1];
  const float* W1     = (const float*)d_in[2];
  const float* b1     = (const float*)d_in[3];
  const float* W2     = (const float*)d_in[4];
  const float* b2     = (const float*)d_in[5];
  const float* Wout   = (const float*)d_in[6];
  const float* bout   = (const float*)d_in[7];
  float* out = (float*)d_out;

  // Workspace layout (~153.4 MB). Order chosen so gemm256's harmless
  // 2-tile over-advance reads (<=4 KB past H2 / WOT) land inside ws.
  char* p = (char*)d_ws;
  u16* XB  = (u16*)p; p += (size_t)MROWS * XDIM  * 2;   // 25.2 MB
  u16* WOT = (u16*)p; p += (size_t)VPAD  * EMBED * 2;   // 103.0 MB (over-read -> H1)
  u16* H1  = (u16*)p; p += (size_t)MROWS * EMBED * 2;   //  8.4 MB
  u16* H2  = (u16*)p; p += (size_t)MROWS * EMBED * 2;   //  8.4 MB (over-read -> W1T)
  u16* W1T = (u16*)p; p += (size_t)EMBED * XDIM  * 2;   //  6.3 MB
  u16* W2T = (u16*)p; p += (size_t)EMBED * EMBED * 2;   //  2.1 MB

  hipFuncSetAttribute((const void*)gemm256,
                      hipFuncAttributeMaxDynamicSharedMemorySize, 98304);

  gather_x<<<MROWS, 256, 0, stream>>>(tokens, E, XB);
  transpose_cvt<<<dim3(EMBED/32, XDIM/32),  256, 0, stream>>>(W1,   W1T, XDIM,  EMBED);
  transpose_cvt<<<dim3(EMBED/32, EMBED/32), 256, 0, stream>>>(W2,   W2T, EMBED, EMBED);
  transpose_cvt<<<dim3(VPAD/32,  EMBED/32), 256, 0, stream>>>(Wout, WOT, EMBED, VOCAB);

  gemm_bt<0><<<dim3(EMBED/128, MROWS/128), 256, 0, stream>>>(XB, W1T, b1, H1, XDIM,  EMBED);
  gemm_bt<0><<<dim3(EMBED/128, MROWS/128), 256, 0, stream>>>(H1, W2T, b2, H2, EMBED, EMBED);

  gemm256<<<NWG, 512, 98304, stream>>>(H2, WOT, bout, out);
}

// Round 10
// 810.802 us; speedup vs baseline: 6.0113x; 1.0015x over previous
//
#include <hip/hip_runtime.h>
#include <hip/hip_bf16.h>

// Problem constants (fixed by reference)
#define SEQ    2048
#define BATCH  2
#define MROWS  (SEQ*BATCH)    // 4096
#define EMBED  1024
#define KCTX   3
#define XDIM   (KCTX*EMBED)   // 3072
#define VOCAB  50257
#define VPAD   50304          // Wout^T rows allocated (multiple of 128)
#define GK     1024           // K of the logits GEMM
#define NT2    32             // K-tiles of BK=32
#define NBLKN  197            // ceil(VOCAB/256)
#define NWG    (16*NBLKN)     // 3152 blocks, divisible by 8

using u16 = unsigned short;
typedef __attribute__((ext_vector_type(8))) short   frag_ab;  // 8 bf16
typedef __attribute__((ext_vector_type(4))) float   frag_cd;  // 4 f32

__device__ __forceinline__ u16 f2bf(float f) {
  union { float f; unsigned u; } v; v.f = f;
  unsigned r = v.u + 0x7fffu + ((v.u >> 16) & 1u);
  return (u16)(r >> 16);
}

__device__ __forceinline__ void gload16(const u16* g, const u16* l) {
  __builtin_amdgcn_global_load_lds((const __attribute__((address_space(1))) void*)g,
                                   (__attribute__((address_space(3))) void*)l, 16, 0, 0);
}

// ---------------------------------------------------------------------------
// Gather: XB[r][i*1024+c] = bf16(E[tok(r,i)][c]); r = s*BATCH+b
// ---------------------------------------------------------------------------
__global__ void gather_x(const int* __restrict__ tokens,
                         const float* __restrict__ E,
                         u16* __restrict__ XB) {
  const int r = blockIdx.x;
  const int s = r >> 1, b = r & 1;
  #pragma unroll
  for (int i = 0; i < KCTX; ++i) {
    int t = s + i - (KCTX - 1);
    int tok = (t >= 0) ? tokens[t * BATCH + b] : 0;
    const float* src = &E[(size_t)tok * EMBED];
    u16* dst = &XB[(size_t)r * XDIM + i * EMBED];
    int c = threadIdx.x * 4;
    float4 v = *(const float4*)&src[c];
    u16 o[4] = { f2bf(v.x), f2bf(v.y), f2bf(v.z), f2bf(v.w) };
    *(ulong1*)&dst[c] = *(ulong1*)o;
  }
}

// ---------------------------------------------------------------------------
// Transpose + f32->bf16: W (K x N) -> WT (Npad x K). n >= N writes 0.
// ---------------------------------------------------------------------------
__global__ void transpose_cvt(const float* __restrict__ W,
                              u16* __restrict__ WT,
                              int K, int N) {
  __shared__ float tile[32][33];
  const int nb = blockIdx.x * 32, kb = blockIdx.y * 32;
  const int tx = threadIdx.x & 31, ty = threadIdx.x >> 5;
  #pragma unroll
  for (int i = 0; i < 32; i += 8) {
    int k = kb + ty + i, n = nb + tx;
    tile[ty + i][tx] = (n < N) ? W[(size_t)k * N + n] : 0.f;
  }
  __syncthreads();
  #pragma unroll
  for (int i = 0; i < 32; i += 8) {
    int n = nb + ty + i, k = kb + tx;
    WT[(size_t)n * K + k] = f2bf(tile[tx][ty + i]);
  }
}

// ---------------------------------------------------------------------------
// 128x128-tile GEMM (2-phase) for the two small GEMMs. Verified round 1.
// ---------------------------------------------------------------------------
template<int EPI>
__global__ __launch_bounds__(256, 2)
void gemm_bt(const u16* __restrict__ A, const u16* __restrict__ BT,
             const float* __restrict__ bias, void* __restrict__ Cout,
             int K, int Nout) {
  __shared__ u16 lA[128 * 64];
  __shared__ u16 lB[128 * 64];
  const int tid  = threadIdx.x;
  const int wave = tid >> 6, lane = tid & 63;
  const int m0 = blockIdx.y * 128;
  const int n0 = blockIdx.x * 128;
  const int wm = (wave >> 1) * 64;
  const int wn = (wave & 1) * 64;

  frag_cd acc[4][4];
  #pragma unroll
  for (int i = 0; i < 4; ++i)
    #pragma unroll
    for (int j = 0; j < 4; ++j)
      acc[i][j] = (frag_cd)0.f;

  const int srow = lane >> 3;
  const int skc  = (lane & 7) * 8;

  for (int k0 = 0; k0 < K; k0 += 64) {
    #pragma unroll
    for (int i = 0; i < 4; ++i) {
      int chunk = wave * 4 + i;
      int r = chunk * 8 + srow;
      const u16* ga = &A [(size_t)(m0 + r) * K + k0 + skc];
      const u16* gb = &BT[(size_t)(n0 + r) * K + k0 + skc];
      gload16(ga, &lA[chunk * 512 + lane * 8]);
      gload16(gb, &lB[chunk * 512 + lane * 8]);
    }
    __syncthreads();

    #pragma unroll
    for (int kk = 0; kk < 2; ++kk) {
      const int ko = kk * 32 + (lane >> 4) * 8;
      frag_ab af[4], bfr[4];
      #pragma unroll
      for (int i = 0; i < 4; ++i) {
        af[i]  = *(const frag_ab*)&lA[(wm + i * 16 + (lane & 15)) * 64 + ko];
        bfr[i] = *(const frag_ab*)&lB[(wn + i * 16 + (lane & 15)) * 64 + ko];
      }
      #pragma unroll
      for (int i = 0; i < 4; ++i)
        #pragma unroll
        for (int j = 0; j < 4; ++j)
          acc[i][j] = __builtin_amdgcn_mfma_f32_16x16x32_bf16(
              af[i], bfr[j], acc[i][j], 0, 0, 0);
    }
    __syncthreads();
  }

  const int cr = (lane >> 4) * 4;
  const int cc = lane & 15;
  if (EPI == 0) {
    u16* H = (u16*)Cout;
    #pragma unroll
    for (int j = 0; j < 4; ++j) {
      int colg = n0 + wn + j * 16 + cc;
      float bv = bias[colg];
      #pragma unroll
      for (int i = 0; i < 4; ++i)
        #pragma unroll
        for (int t = 0; t < 4; ++t) {
          int rowg = m0 + wm + i * 16 + cr + t;
          float v = acc[i][j][t] + bv;
          v = v / (1.f + __expf(-v));
          H[(size_t)rowg * Nout + colg] = f2bf(v);
        }
    }
  } else {
    float* O = (float*)Cout;
    #pragma unroll
    for (int j = 0; j < 4; ++j) {
      int colg = n0 + wn + j * 16 + cc;
      if (colg < Nout) {
        float bv = bias[colg];
        #pragma unroll
        for (int i = 0; i < 4; ++i)
          #pragma unroll
          for (int t = 0; t < 4; ++t) {
            int rowg = m0 + wm + i * 16 + cr + t;
            O[(size_t)rowg * Nout + colg] = acc[i][j][t] + bv;
          }
      }
    }
  }
}

// ---------------------------------------------------------------------------
// Logits GEMM, round 10: r9 + counted-lgkmcnt ds_read/MFMA interleave.
// Reads issue wF0-3 then hF0-7; MFMA group k (4 MFMAs on acc[k][*]) gated by
// lgkmcnt(7-k) so the LDS pipe streams while the matrix pipe drains.
// sched_barrier(0) after each wait (rule #18: register-only MFMAs hoist past
// volatile asm otherwise). Depth-2 vmcnt(4) staging + 3 parities + full-line
// LDS epilogue unchanged from r9 (WRITE_SIZE at ideal).
// ---------------------------------------------------------------------------
#define BARR   asm volatile("s_barrier" ::: "memory")
#define VMCNT4 asm volatile("s_waitcnt vmcnt(4)" ::: "memory")
#define LGKMC(N) asm volatile("s_waitcnt lgkmcnt(" #N ")" ::: "memory")
#define SCHED0 __builtin_amdgcn_sched_barrier(0)
#define PRIO1  __builtin_amdgcn_s_setprio(1)
#define PRIO0  __builtin_amdgcn_s_setprio(0)

#define DSREAD(DST, AREG, IMM) \
  asm volatile("ds_read_b128 %0, %1 offset:%2" : "=v"(DST) : "v"(AREG), "i"(IMM))

#define ADV { pa0 += 32; pa1 += 32; pb0 += 32; pb1 += 32; }

#define MFMA4(MF) { \
  _Pragma("unroll") for (int nf = 0; nf < 4; ++nf) \
    acc[MF][nf] = __builtin_amdgcn_mfma_f32_16x16x32_bf16(hF[MF], wF[nf], acc[MF][nf], 0, 0, 0); }

// One K-tile: REGH/REGW = ds_read base regs, HIMM/WIMM = read parity bytes,
// WP = stage-dest parity bytes.
#define KT(REGH, REGW, HIMM, WIMM, WP) { \
  VMCNT4; BARR; \
  gload16(pa0, (const u16*)(smraw + (WP)         + stoff)); \
  gload16(pa1, (const u16*)(smraw + (WP) +  8192 + stoff)); \
  gload16(pb0, (const u16*)(smraw + (WP) + 16384 + stoff)); \
  gload16(pb1, (const u16*)(smraw + (WP) + 24576 + stoff)); \
  ADV; \
  DSREAD(wF[0], REGW, (WIMM) + 0*1024); \
  DSREAD(wF[1], REGW, (WIMM) + 1*1024); \
  DSREAD(wF[2], REGW, (WIMM) + 2*1024); \
  DSREAD(wF[3], REGW, (WIMM) + 3*1024); \
  DSREAD(hF[0], REGH, (HIMM) + 0*1024); \
  DSREAD(hF[1], REGH, (HIMM) + 1*1024); \
  DSREAD(hF[2], REGH, (HIMM) + 2*1024); \
  DSREAD(hF[3], REGH, (HIMM) + 3*1024); \
  DSREAD(hF[4], REGH, (HIMM) + 4*1024); \
  DSREAD(hF[5], REGH, (HIMM) + 5*1024); \
  DSREAD(hF[6], REGH, (HIMM) + 6*1024); \
  DSREAD(hF[7], REGH, (HIMM) + 7*1024); \
  PRIO1; \
  LGKMC(7); SCHED0; MFMA4(0); \
  LGKMC(6); SCHED0; MFMA4(1); \
  LGKMC(5); SCHED0; MFMA4(2); \
  LGKMC(4); SCHED0; MFMA4(3); \
  LGKMC(3); SCHED0; MFMA4(4); \
  LGKMC(2); SCHED0; MFMA4(5); \
  LGKMC(1); SCHED0; MFMA4(6); \
  LGKMC(0); SCHED0; MFMA4(7); \
  PRIO0; SCHED0; }

__global__ __launch_bounds__(512, 2)
void gemm256(const u16* __restrict__ A, const u16* __restrict__ BT,
             const float* __restrict__ bias, float* __restrict__ O) {
  extern __shared__ char smraw[];

  // Bijective chunked XCD swizzle; M-innermost so one XCD reuses one B-panel.
  const int bid = blockIdx.x;
  const int wg  = (bid & 7) * (NWG / 8) + (bid >> 3);
  const int m0  = (wg & 15) * 256;
  const int n0  = (wg >> 4) * 256;

  const int tid  = threadIdx.x;
  const int lane = tid & 63, wave = tid >> 6;
  const int wm = wave >> 2, wn = wave & 3;   // 2 x 4 waves

  // ---- staging constants (gload_lds dest = base + lane*16: linear) ----
  const int stoff = wave * 1024 + lane * 16;               // LDS byte offset
  const int srow  = wave * 16 + (lane >> 2);               // tile row (+128 for *1)
  const int ke    = ((lane & 3) ^ ((lane >> 3) & 3)) * 8;  // pre-swz k elems

  const u16* pa0 = A + (size_t)(m0 + srow      ) * GK + ke;
  const u16* pa1 = A + (size_t)(m0 + srow + 128) * GK + ke;
  int rb0 = n0 + srow;       if (rb0 > VPAD - 1) rb0 = VPAD - 1;
  int rb1 = n0 + srow + 128; if (rb1 > VPAD - 1) rb1 = VPAD - 1;
  const u16* pb0 = BT + (size_t)rb0 * GK + ke;
  const u16* pb1 = BT + (size_t)rb1 * GK + ke;

  // ---- ds_read base regs (swizzle: 16B-slot ^= (row>>1)&3) ----
  const unsigned dynbase = (unsigned)(size_t)(__attribute__((address_space(3))) char*)smraw;
  const int c = lane & 15, q = lane >> 4;
  const unsigned swq  = ((unsigned)q << 4) ^ (((unsigned)(c >> 1) & 3u) << 4);
  const unsigned regH_lo = dynbase + (unsigned)((wm * 128 + c) * 64) + swq;            // H2 rows (m)
  const unsigned regW_lo = dynbase + 16384u + (unsigned)((wn * 64 + c) * 64) + swq;    // WOT rows (vocab)
  const unsigned regH_hi = regH_lo + 65536u;   // parity 2
  const unsigned regW_hi = regW_lo + 65536u;

  frag_ab hF[8], wF[4];
  frag_cd acc[8][4];
  #pragma unroll
  for (int i = 0; i < 8; ++i)
    #pragma unroll
    for (int j = 0; j < 4; ++j)
      acc[i][j] = (frag_cd)0.f;

  // ---- prologue: stage tiles 0 -> par0, 1 -> par1 ----
  gload16(pa0, (const u16*)(smraw +     0 + stoff));
  gload16(pa1, (const u16*)(smraw +  8192 + stoff));
  gload16(pb0, (const u16*)(smraw + 16384 + stoff));
  gload16(pb1, (const u16*)(smraw + 24576 + stoff));
  ADV;
  gload16(pa0, (const u16*)(smraw + 32768 +     0 + stoff));
  gload16(pa1, (const u16*)(smraw + 32768 +  8192 + stoff));
  gload16(pb0, (const u16*)(smraw + 32768 + 16384 + stoff));
  gload16(pb1, (const u16*)(smraw + 32768 + 24576 + stoff));
  ADV;

  // ---- main loop: 32 K-tiles = 10 x (par0,par1,par2) + par0,par1 ----
  #pragma unroll 1
  for (int tt = 0; tt < 10; ++tt) {
    KT(regH_lo, regW_lo,     0,     0, 65536);   // read par0, stage -> par2
    KT(regH_lo, regW_lo, 32768, 32768,     0);   // read par1, stage -> par0
    KT(regH_hi, regW_hi,     0,     0, 32768);   // read par2, stage -> par1
  }
  KT(regH_lo, regW_lo,     0,     0, 65536);     // t=30
  KT(regH_lo, regW_lo, 32768, 32768,     0);     // t=31 (stages are garbage, in-ws)

  // drain garbage stages + all LDS ops, then barrier before LDS reuse
  asm volatile("s_waitcnt vmcnt(0) lgkmcnt(0)" ::: "memory");
  BARR;

  // ---- epilogue: re-layout through LDS -> full-128B-line stores ----
  float* lfs = (float*)smraw;
  const int colg = n0 + wn * 64 + c * 4;
  #pragma unroll
  for (int mf = 0; mf < 8; ++mf) {
    const int lbase = wave * 1088 + (mf & 1) * 8704;
    #pragma unroll
    for (int nf = 0; nf < 4; ++nf)
      #pragma unroll
      for (int t = 0; t < 4; ++t)
        lfs[lbase + (q * 4 + t) * 68 + nf * 16 + c] = acc[mf][nf][t];
    #pragma unroll
    for (int p = 0; p < 4; ++p) {
      frag_cd v = *(const frag_cd*)&lfs[lbase + (p * 4 + q) * 68 + c * 4];
      const int rowg = m0 + wm * 128 + mf * 16 + p * 4 + q;
      if (colg + 3 < VOCAB) {
        frag_cd bv = *(const frag_cd*)&bias[colg];
        v += bv;
        *(frag_cd*)&O[(size_t)rowg * VOCAB + colg] = v;
      } else {
        #pragma unroll
        for (int t = 0; t < 4; ++t)
          if (colg + t < VOCAB)
            O[(size_t)rowg * VOCAB + colg + t] = v[t] + bias[colg + t];
      }
    }
  }
}

// ---------------------------------------------------------------------------
extern "C" void kernel_launch(void* const* d_in, const int* in_sizes, int n_in,
                              void* d_out, int out_size, void* d_ws, size_t ws_size,
                              hipStream_t stream) {
  const int*   tokens = (const int*)  d_in[0];
  const float* E      = (const float*)d_in[1];
  const float* W1     = (const float*)d_in[2];
  const float* b1     = (const float*)d_in[3];
  const float* W2     = (const float*)d_in[4];
  const float* b2     = (const float*)d_in[5];
  const float* Wout   = (const float*)d_in[6];
  const float* bout   = (const float*)d_in[7];
  float* out = (float*)d_out;

  // Workspace layout (~153.4 MB). Order chosen so gemm256's harmless
  // 2-tile over-advance reads (<=4 KB past H2 / WOT) land inside ws.
  char* p = (char*)d_ws;
  u16* XB  = (u16*)p; p += (size_t)MROWS * XDIM  * 2;   // 25.2 MB
  u16* WOT = (u16*)p; p += (size_t)VPAD  * EMBED * 2;   // 103.0 MB (over-read -> H1)
  u16* H1  = (u16*)p; p += (size_t)MROWS * EMBED * 2;   //  8.4 MB
  u16* H2  = (u16*)p; p += (size_t)MROWS * EMBED * 2;   //  8.4 MB (over-read -> W1T)
  u16* W1T = (u16*)p; p += (size_t)EMBED * XDIM  * 2;   //  6.3 MB
  u16* W2T = (u16*)p; p += (size_t)EMBED * EMBED * 2;   //  2.1 MB

  hipFuncSetAttribute((const void*)gemm256,
                      hipFuncAttributeMaxDynamicSharedMemorySize, 98304);

  gather_x<<<MROWS, 256, 0, stream>>>(tokens, E, XB);
  transpose_cvt<<<dim3(EMBED/32, XDIM/32),  256, 0, stream>>>(W1,   W1T, XDIM,  EMBED);
  transpose_cvt<<<dim3(EMBED/32, EMBED/32), 256, 0, stream>>>(W2,   W2T, EMBED, EMBED);
  transpose_cvt<<<dim3(VPAD/32,  EMBED/32), 256, 0, stream>>>(Wout, WOT, EMBED, VOCAB);

  gemm_bt<0><<<dim3(EMBED/128, MROWS/128), 256, 0, stream>>>(XB, W1T, b1, H1, XDIM,  EMBED);
  gemm_bt<0><<<dim3(EMBED/128, MROWS/128), 256, 0, stream>>>(H1, W2T, b2, H2, EMBED, EMBED);

  gemm256<<<NWG, 512, 98304, stream>>>(H2, WOT, bout, out);
}